// Round 1
// 760.192 us; speedup vs baseline: 1.1451x; 1.1451x over previous
//
#include <hip/hip_runtime.h>
#include <hip/hip_bf16.h>
#include <cstring>
#include <cstdint>

#define N_NODES 100000
#define N_EDGES 1600000
#define HID 128
#define TOT (N_NODES * HID)   // 12,800,000

// ---------------- workspace layout (bytes) ----------------
// aggbuf  f32 [N,128]   @ 0           51,200,000
// hbf     bf16[N,128]   @ 51,200,000  25,600,000
// counts  int [N]       @ 76,800,000     400,000
// partial int [N]       @ 77,200,000     400,000
// bsum    int [512]     @ 77,600,000       2,048
// offsets int [N+1]     @ 77,602,048     400,128
// cursor  int [N]       @ 78,002,176     400,000
// dinv    f32 [N]       @ 78,402,176     400,000
// sorted  int2[E]       @ 78,802,176  12,800,000
// total ~91.6 MB

// ---------------- helpers ----------------
__device__ __forceinline__ float2 ld2(const float* p) { return *(const float2*)p; }
__device__ __forceinline__ float2 ld2(const __hip_bfloat16* p) {
    const __hip_bfloat162 h = *(const __hip_bfloat162*)p;
    return make_float2(__bfloat162float(h.x), __bfloat162float(h.y));
}

__device__ __forceinline__ void store8(float* p, const float* v) {
    *(float4*)(p)     = make_float4(v[0], v[1], v[2], v[3]);
    *(float4*)(p + 4) = make_float4(v[4], v[5], v[6], v[7]);
}
__device__ __forceinline__ void store8(__hip_bfloat16* p, const float* v) {
    union { unsigned short us[8]; uint4 q; } u;
#pragma unroll
    for (int i = 0; i < 8; ++i) {
        __hip_bfloat16 b = __float2bfloat16(v[i]);
        unsigned short raw;
        memcpy(&raw, &b, 2);
        u.us[i] = raw;
    }
    *(uint4*)p = u.q;
}

// ---------------- CSR build ----------------
__global__ void k_count(const int* __restrict__ dst, int* __restrict__ counts) {
    int e = blockIdx.x * 256 + threadIdx.x;
    if (e < N_EDGES) atomicAdd(&counts[dst[e]], 1);
}

__global__ void k_scan_block(const int* __restrict__ counts, int* __restrict__ partial,
                             int* __restrict__ bsum) {
    __shared__ int s[256];
    int i = blockIdx.x * 256 + threadIdx.x;
    int v = (i < N_NODES) ? counts[i] : 0;
    s[threadIdx.x] = v;
    __syncthreads();
    for (int off = 1; off < 256; off <<= 1) {
        int t = (threadIdx.x >= off) ? s[threadIdx.x - off] : 0;
        __syncthreads();
        s[threadIdx.x] += t;
        __syncthreads();
    }
    if (i < N_NODES) partial[i] = s[threadIdx.x] - v;   // exclusive within block
    if (threadIdx.x == 255) bsum[blockIdx.x] = s[255];
}

__global__ void k_scan_sums(int* __restrict__ bsum, int nb) {
    __shared__ int s[512];
    int v = (threadIdx.x < nb) ? bsum[threadIdx.x] : 0;
    s[threadIdx.x] = v;
    __syncthreads();
    for (int off = 1; off < 512; off <<= 1) {
        int t = (threadIdx.x >= off) ? s[threadIdx.x - off] : 0;
        __syncthreads();
        s[threadIdx.x] += t;
        __syncthreads();
    }
    if (threadIdx.x < nb) bsum[threadIdx.x] = s[threadIdx.x] - v;  // exclusive
}

__global__ void k_finalize(const int* __restrict__ counts, const int* __restrict__ partial,
                           const int* __restrict__ bsum, int* __restrict__ offsets,
                           int* __restrict__ cursor, float* __restrict__ dinv) {
    int i = blockIdx.x * 256 + threadIdx.x;
    if (i < N_NODES) {
        int o = partial[i] + bsum[blockIdx.x];
        offsets[i] = o;
        cursor[i] = o;
        dinv[i] = rsqrtf((float)(counts[i] + 1));  // deg = in-degree + self loop
    }
    if (i == 0) offsets[N_NODES] = N_EDGES;
}

__global__ void k_scatter(const int* __restrict__ src, const int* __restrict__ dst,
                          const float* __restrict__ dinv, int* __restrict__ cursor,
                          int2* __restrict__ sorted) {
    int e = blockIdx.x * 256 + threadIdx.x;
    if (e < N_EDGES) {
        int s = src[e], d = dst[e];
        int pos = atomicAdd(&cursor[d], 1);
        float c = dinv[s] * dinv[d];
        sorted[pos] = make_int2(s, __float_as_int(c));
    }
}

// ---------------- aggregation: one wave per node, 2 features per lane ----------------
// Edge loop unrolled x8 with predicated (clamped-index) tail so 8 independent
// gathers are in flight per wave before the first s_waitcnt — the previous
// serial loop (VGPR_Count=8!) had exactly one gather outstanding and was
// latency-bound (VALUBusy 13%, hbm 32%, MfmaUtil 0).
template <typename T>
__global__ __launch_bounds__(256) void k_aggregate(const T* __restrict__ X,
                                                   const int* __restrict__ offsets,
                                                   const int2* __restrict__ sorted,
                                                   const float* __restrict__ dinv,
                                                   float* __restrict__ out) {
    int node = (blockIdx.x * 256 + threadIdx.x) >> 6;
    int lane = threadIdx.x & 63;
    if (node >= N_NODES) return;
    int f = lane * 2;
    float di = dinv[node];
    float sc = di * di;
    float2 xi = ld2(X + (size_t)node * HID + f);
    float a0 = sc * xi.x, a1 = sc * xi.y;
    int e0 = offsets[node], e1 = offsets[node + 1];
    for (int e = e0; e < e1; e += 8) {
        int2 sv[8];
        float2 xs[8];
#pragma unroll
        for (int i = 0; i < 8; ++i) {
            int ee = e + i;
            sv[i] = sorted[(ee < e1) ? ee : (e1 - 1)];   // clamped: load always valid
        }
#pragma unroll
        for (int i = 0; i < 8; ++i) {
            xs[i] = ld2(X + (size_t)sv[i].x * HID + f);  // 8 gathers batched in flight
        }
#pragma unroll
        for (int i = 0; i < 8; ++i) {
            float c = (e + i < e1) ? __int_as_float(sv[i].y) : 0.f;  // kill tail slots
            a0 = fmaf(c, xs[i].x, a0);
            a1 = fmaf(c, xs[i].y, a1);
        }
    }
    *(float2*)(out + (size_t)node * HID + f) = make_float2(a0, a1);
}

// ---------------- GEMM: C[N,128] = A[N,128] @ W[128,128] + bias (optional ELU) ----------
// block: 256 threads, tile 128 rows x 128 cols, K chunked by 16 through LDS.
// thread (tx,ty) computes 8 rows x 8 cols.
template <int ACT, typename OutT>
__global__ __launch_bounds__(256) void k_gemm(const float* __restrict__ A,
                                              const float* __restrict__ W,
                                              const float* __restrict__ bias,
                                              OutT* __restrict__ out) {
    __shared__ float Wl[16][128];
    __shared__ float Al[128][16];
    int t = threadIdx.x;
    int R = blockIdx.x * 128;
    int tx = t & 15, ty = t >> 4;
    int c0 = tx * 8;
    int r0 = ty * 8;
    float acc[8][8] = {};

    for (int k0 = 0; k0 < 128; k0 += 16) {
        // stage W chunk [k0..k0+16) x 128 : 512 float4, 2 per thread
        {
            const float4* Wg = (const float4*)(W + k0 * 128);
            ((float4*)&Wl[0][0])[t] = Wg[t];
            ((float4*)&Wl[0][0])[t + 256] = Wg[t + 256];
        }
        // stage A chunk 128 rows x 16 cols : 512 float4, 2 per thread
        {
#pragma unroll
            for (int ii = 0; ii < 2; ++ii) {
                int id = t + ii * 256;
                int row = id >> 2, c4 = (id & 3) * 4;
                int gr = R + row;
                float4 v = make_float4(0.f, 0.f, 0.f, 0.f);
                if (gr < N_NODES) v = *(const float4*)(A + (size_t)gr * HID + k0 + c4);
                *(float4*)(&Al[row][c4]) = v;
            }
        }
        __syncthreads();

#pragma unroll
        for (int kk4 = 0; kk4 < 4; ++kk4) {
            float4 av4[8];
#pragma unroll
            for (int j = 0; j < 8; ++j) av4[j] = *(const float4*)(&Al[r0 + j][kk4 * 4]);
            const float* av = (const float*)av4;  // av[j*4 + kk]
#pragma unroll
            for (int kk = 0; kk < 4; ++kk) {
                float4 b0 = *(const float4*)(&Wl[kk4 * 4 + kk][c0]);
                float4 b1 = *(const float4*)(&Wl[kk4 * 4 + kk][c0 + 4]);
#pragma unroll
                for (int j = 0; j < 8; ++j) {
                    float a = av[j * 4 + kk];
                    acc[j][0] = fmaf(a, b0.x, acc[j][0]);
                    acc[j][1] = fmaf(a, b0.y, acc[j][1]);
                    acc[j][2] = fmaf(a, b0.z, acc[j][2]);
                    acc[j][3] = fmaf(a, b0.w, acc[j][3]);
                    acc[j][4] = fmaf(a, b1.x, acc[j][4]);
                    acc[j][5] = fmaf(a, b1.y, acc[j][5]);
                    acc[j][6] = fmaf(a, b1.z, acc[j][6]);
                    acc[j][7] = fmaf(a, b1.w, acc[j][7]);
                }
            }
        }
        __syncthreads();
    }

    float bcol[8];
#pragma unroll
    for (int c = 0; c < 8; ++c) bcol[c] = bias[c0 + c];
#pragma unroll
    for (int j = 0; j < 8; ++j) {
        int gr = R + r0 + j;
        if (gr >= N_NODES) continue;
        float v[8];
#pragma unroll
        for (int c = 0; c < 8; ++c) {
            float vv = acc[j][c] + bcol[c];
            if (ACT == 1) vv = (vv > 0.f) ? vv : expm1f(vv);  // ELU(alpha=1)
            v[c] = vv;
        }
        store8(out + (size_t)gr * HID + c0, v);
    }
}

// ---------------- Threefry-2x32 (20 rounds), key = (0, 42) ----------------
#define EPS_PARTITIONABLE 1

__device__ __forceinline__ unsigned rotl32(unsigned x, int r) {
    return (x << r) | (x >> (32 - r));
}

__device__ __forceinline__ void threefry2x32(unsigned x0, unsigned x1, unsigned& o0,
                                             unsigned& o1) {
    const unsigned ks0 = 0u, ks1 = 42u, ks2 = 0x1BD11BDAu ^ 42u;
    x0 += ks0;
    x1 += ks1;
    x0 += x1; x1 = rotl32(x1, 13); x1 ^= x0;
    x0 += x1; x1 = rotl32(x1, 15); x1 ^= x0;
    x0 += x1; x1 = rotl32(x1, 26); x1 ^= x0;
    x0 += x1; x1 = rotl32(x1, 6);  x1 ^= x0;
    x0 += ks1; x1 += ks2 + 1u;
    x0 += x1; x1 = rotl32(x1, 17); x1 ^= x0;
    x0 += x1; x1 = rotl32(x1, 29); x1 ^= x0;
    x0 += x1; x1 = rotl32(x1, 16); x1 ^= x0;
    x0 += x1; x1 = rotl32(x1, 24); x1 ^= x0;
    x0 += ks2; x1 += ks0 + 2u;
    x0 += x1; x1 = rotl32(x1, 13); x1 ^= x0;
    x0 += x1; x1 = rotl32(x1, 15); x1 ^= x0;
    x0 += x1; x1 = rotl32(x1, 26); x1 ^= x0;
    x0 += x1; x1 = rotl32(x1, 6);  x1 ^= x0;
    x0 += ks0; x1 += ks1 + 3u;
    x0 += x1; x1 = rotl32(x1, 17); x1 ^= x0;
    x0 += x1; x1 = rotl32(x1, 29); x1 ^= x0;
    x0 += x1; x1 = rotl32(x1, 16); x1 ^= x0;
    x0 += x1; x1 = rotl32(x1, 24); x1 ^= x0;
    x0 += ks1; x1 += ks2 + 4u;
    x0 += x1; x1 = rotl32(x1, 13); x1 ^= x0;
    x0 += x1; x1 = rotl32(x1, 15); x1 ^= x0;
    x0 += x1; x1 = rotl32(x1, 26); x1 ^= x0;
    x0 += x1; x1 = rotl32(x1, 6);  x1 ^= x0;
    x0 += ks2; x1 += ks0 + 5u;
    o0 = x0;
    o1 = x1;
}

// XLA ErfInv (f32, Giles) — matches CPU XLA expansion used by jax.random.normal.
__device__ __forceinline__ float erfinv_f32(float x) {
    float w = -log1pf(-x * x);
    float p;
    if (w < 5.0f) {
        w -= 2.5f;
        p = 2.81022636e-08f;
        p = fmaf(p, w, 3.43273939e-07f);
        p = fmaf(p, w, -3.5233877e-06f);
        p = fmaf(p, w, -4.39150654e-06f);
        p = fmaf(p, w, 0.00021858087f);
        p = fmaf(p, w, -0.00125372503f);
        p = fmaf(p, w, -0.00417768164f);
        p = fmaf(p, w, 0.246640727f);
        p = fmaf(p, w, 1.50140941f);
    } else {
        w = sqrtf(w) - 3.0f;
        p = -0.000200214257f;
        p = fmaf(p, w, 0.000100950558f);
        p = fmaf(p, w, 0.00134934322f);
        p = fmaf(p, w, -0.00367342844f);
        p = fmaf(p, w, 0.00573950773f);
        p = fmaf(p, w, -0.0076224613f);
        p = fmaf(p, w, 0.00943887047f);
        p = fmaf(p, w, 1.00167406f);
        p = fmaf(p, w, 2.83297682f);
    }
    return p * x;
}

__global__ __launch_bounds__(256) void k_sample(const float* __restrict__ mu,
                                                const float* __restrict__ lv,
                                                float* __restrict__ z) {
    int j = blockIdx.x * 256 + threadIdx.x;
    if (j >= TOT) return;
    unsigned o0, o1, bits;
#if EPS_PARTITIONABLE
    threefry2x32(0u, (unsigned)j, o0, o1);
    bits = o0 ^ o1;
#else
    const int H = TOT / 2;
    if (j < H) {
        threefry2x32((unsigned)j, (unsigned)(j + H), o0, o1);
        bits = o0;
    } else {
        threefry2x32((unsigned)(j - H), (unsigned)j, o0, o1);
        bits = o1;
    }
#endif
    // uniform in [minval, 1) with minval = nextafter(-1,0); scale rounds to 2.0f
    float f = __uint_as_float((bits >> 9) | 0x3f800000u) - 1.0f;
    float u = f * 2.0f - 0.99999994f;
    u = fmaxf(u, -0.99999994f);
    float eps = 1.41421356f * erfinv_f32(u);
    z[j] = fmaf(eps, expf(0.5f * lv[j]), mu[j]);
}

// ---------------- launch ----------------
extern "C" void kernel_launch(void* const* d_in, const int* in_sizes, int n_in,
                              void* d_out, int out_size, void* d_ws, size_t ws_size,
                              hipStream_t stream) {
    const float* x = (const float*)d_in[0];
    const int* ei = (const int*)d_in[1];
    const float* W1 = (const float*)d_in[2];
    const float* b1 = (const float*)d_in[3];
    const float* Wmu = (const float*)d_in[4];
    const float* bmu = (const float*)d_in[5];
    const float* Wlv = (const float*)d_in[6];
    const float* blv = (const float*)d_in[7];

    float* z = (float*)d_out;
    float* mu = z + (size_t)TOT;
    float* lv = z + 2 * (size_t)TOT;

    char* ws = (char*)d_ws;
    float* aggbuf = (float*)(ws + 0ull);
    __hip_bfloat16* hbf = (__hip_bfloat16*)(ws + 51200000ull);
    int* counts = (int*)(ws + 76800000ull);
    int* partial = (int*)(ws + 77200000ull);
    int* bsum = (int*)(ws + 77600000ull);
    int* offsets = (int*)(ws + 77602048ull);
    int* cursor = (int*)(ws + 78002176ull);
    float* dinv = (float*)(ws + 78402176ull);
    int2* sorted = (int2*)(ws + 78802176ull);

    const int* src = ei;
    const int* dst = ei + N_EDGES;

    const int NBLK = (N_NODES + 255) / 256;  // 391

    hipMemsetAsync(counts, 0, N_NODES * sizeof(int), stream);
    k_count<<<(N_EDGES + 255) / 256, 256, 0, stream>>>(dst, counts);
    k_scan_block<<<NBLK, 256, 0, stream>>>(counts, partial, bsum);
    k_scan_sums<<<1, 512, 0, stream>>>(bsum, NBLK);
    k_finalize<<<NBLK, 256, 0, stream>>>(counts, partial, bsum, offsets, cursor, dinv);
    k_scatter<<<(N_EDGES + 255) / 256, 256, 0, stream>>>(src, dst, dinv, cursor, sorted);

    // layer 1: xa = Agg(x); h = elu(xa @ W1 + b1)  (h stored bf16)
    k_aggregate<float><<<(N_NODES * 64 + 255) / 256, 256, 0, stream>>>(x, offsets, sorted,
                                                                       dinv, aggbuf);
    k_gemm<1, __hip_bfloat16><<<(N_NODES + 127) / 128, 256, 0, stream>>>(aggbuf, W1, b1, hbf);

    // layer 2: ha = Agg(h); mu = ha @ Wmu + bmu; lv = ha @ Wlv + blv
    k_aggregate<__hip_bfloat16><<<(N_NODES * 64 + 255) / 256, 256, 0, stream>>>(
        hbf, offsets, sorted, dinv, aggbuf);
    k_gemm<0, float><<<(N_NODES + 127) / 128, 256, 0, stream>>>(aggbuf, Wmu, bmu, mu);
    k_gemm<0, float><<<(N_NODES + 127) / 128, 256, 0, stream>>>(aggbuf, Wlv, blv, lv);

    // z = mu + eps * exp(0.5*lv)   (eps = threefry-normal, key 42)
    k_sample<<<(TOT + 255) / 256, 256, 0, stream>>>(mu, lv, z);
}